// Round 1
// baseline (187.837 us; speedup 1.0000x reference)
//
#include <hip/hip_runtime.h>
#include <hip/hip_bf16.h>
#include <math.h>

// Problem constants (fixed by reference)
#define NB 32      // B
#define NS 512     // N
#define ND 256     // D == H
#define KC 32      // k-chunk for GEMM staging
#define LDP 132    // padded LDS row stride (floats): keeps float4 alignment, spreads banks
#define LIST_CAP 32768u

// ws layout (floats):
//  M     : 4194304   (B*N*D)  -- adj@context; later reused as 'a' (att1 output)
//  h     : 4194304
//  nrm   : 16384, nsq: 16384, rnrm: 16384
//  rowp  : 4*16384 (per-coltile partial row sums)
//  rrow  : 16384 (1/(row+eps)), diag: 16384, wl: 16384
//  pA1[64], pA2[512], pA3[512], cnt[1], keys[32768], vals[32768]
// total ~34.6 MB

__device__ __forceinline__ float wave_sum(float v) {
  v += __shfl_xor(v, 1, 64);
  v += __shfl_xor(v, 2, 64);
  v += __shfl_xor(v, 4, 64);
  v += __shfl_xor(v, 8, 64);
  v += __shfl_xor(v, 16, 64);
  v += __shfl_xor(v, 32, 64);
  return v;
}

// K1: per-row L2 norms of context; also zero the sparse-list counter.
__global__ __launch_bounds__(256)
void k_norm(const float* __restrict__ ctx, float* __restrict__ nrm,
            float* __restrict__ nsq, float* __restrict__ rnrm,
            unsigned* __restrict__ cnt)
{
  if (blockIdx.x == 0 && threadIdx.x == 0) *cnt = 0u;
  int w = threadIdx.x >> 6, lane = threadIdx.x & 63;
  int g = blockIdx.x * 4 + w;             // row id 0..16383
  float4 v = ((const float4*)ctx)[(size_t)g * 64 + lane];
  float ss = v.x*v.x + v.y*v.y + v.z*v.z + v.w*v.w;
  ss = wave_sum(ss);
  if (lane == 0) {
    float n = sqrtf(ss);
    nrm[g] = n;
    nsq[g] = ss;
    rnrm[g] = 1.f / fmaxf(n, 1e-12f);
  }
}

// K2: gram tiles (ti<=tj only, mirrored). Computes att = cn cn^T per 128x128 tile,
// thresholds, accumulates row sums (+mirror col sums), diag, A2/A3 scalars, and
// pushes rare off-diag nonzeros to a global sparse list.
__global__ __launch_bounds__(256, 2)
void k_gram(const float* __restrict__ ctx, const float* __restrict__ nrm,
            const float* __restrict__ rnrm,
            float* __restrict__ rowp, float* __restrict__ diag,
            float* __restrict__ pA2, float* __restrict__ pA3,
            unsigned* __restrict__ cnt, unsigned* __restrict__ keys,
            float* __restrict__ vals)
{
  __shared__ float lsA[KC * LDP];
  __shared__ float lsB[KC * LDP];
  __shared__ float sred[8];
  const int tid = threadIdx.x;
  const int tx = tid & 15, ty = tid >> 4;
  const int ti = blockIdx.x, tj = blockIdx.y, b = blockIdx.z;
  const int bid = (b * 4 + tj) * 4 + ti;      // unique in [0,512)
  if (ti > tj) {                               // skipped mirror block: zero its partials
    if (tid == 0) { pA2[bid] = 0.f; pA3[bid] = 0.f; }
    return;
  }
  const int i0 = ti * 128, j0 = tj * 128;
  const int rbA = b * NS + i0, rbB = b * NS + j0;
  const bool diagTile = (ti == tj);

  float acc[8][8] = {};
  for (int kc = 0; kc < ND; kc += KC) {
    __syncthreads();
    #pragma unroll
    for (int q = 0; q < 4; ++q) {
      int f4 = q * 256 + tid;
      int row = f4 >> 3, k4 = f4 & 7;
      float4 v = ((const float4*)ctx)[(size_t)(rbA + row) * 64 + (kc >> 2) + k4];
      float s = rnrm[rbA + row];
      lsA[(k4*4+0)*LDP + row] = v.x * s;
      lsA[(k4*4+1)*LDP + row] = v.y * s;
      lsA[(k4*4+2)*LDP + row] = v.z * s;
      lsA[(k4*4+3)*LDP + row] = v.w * s;
    }
    if (!diagTile) {
      #pragma unroll
      for (int q = 0; q < 4; ++q) {
        int f4 = q * 256 + tid;
        int row = f4 >> 3, k4 = f4 & 7;
        float4 v = ((const float4*)ctx)[(size_t)(rbB + row) * 64 + (kc >> 2) + k4];
        float s = rnrm[rbB + row];
        lsB[(k4*4+0)*LDP + row] = v.x * s;
        lsB[(k4*4+1)*LDP + row] = v.y * s;
        lsB[(k4*4+2)*LDP + row] = v.z * s;
        lsB[(k4*4+3)*LDP + row] = v.w * s;
      }
    }
    __syncthreads();
    const float* __restrict__ pBB = diagTile ? lsA : lsB;
    #pragma unroll
    for (int k = 0; k < KC; ++k) {
      const float* pa = lsA + k * LDP + ty * 4;
      const float* pb = pBB + k * LDP + tx * 4;
      float4 a0 = *(const float4*)(pa);
      float4 a1 = *(const float4*)(pa + 64);
      float4 b0 = *(const float4*)(pb);
      float4 b1 = *(const float4*)(pb + 64);
      float ar[8] = {a0.x,a0.y,a0.z,a0.w,a1.x,a1.y,a1.z,a1.w};
      float br[8] = {b0.x,b0.y,b0.z,b0.w,b1.x,b1.y,b1.z,b1.w};
      #pragma unroll
      for (int r = 0; r < 8; ++r)
        #pragma unroll
        for (int c = 0; c < 8; ++c)
          acc[r][c] = fmaf(ar[r], br[c], acc[r][c]);
    }
  }

  // epilogue: threshold, reductions, sparse push
  float nr[8], nc[8];
  #pragma unroll
  for (int r = 0; r < 8; ++r) nr[r] = nrm[rbA + ty*4 + (r&3) + ((r>>2)<<6)];
  #pragma unroll
  for (int c = 0; c < 8; ++c) nc[c] = nrm[rbB + tx*4 + (c&3) + ((c>>2)<<6)];

  float rowsum[8] = {}; float colsum[8] = {};
  float a2 = 0.f, a3 = 0.f;
  #pragma unroll
  for (int r = 0; r < 8; ++r) {
    int n = i0 + ty*4 + (r&3) + ((r>>2)<<6);
    #pragma unroll
    for (int c = 0; c < 8; ++c) {
      int m = j0 + tx*4 + (c&3) + ((c>>2)<<6);
      float v = acc[r][c];
      float adj = (v > 0.3f) ? v : 0.f;
      rowsum[r] += adj;
      colsum[c] += adj;
      float q2 = adj * adj;
      a3 += q2;
      a2 += q2 * nr[r] * nc[c];
      bool isd = diagTile && (n == m);
      if (isd) {
        diag[b * NS + n] = adj;
      } else if (adj > 0.f) {
        unsigned add = diagTile ? 1u : 2u;
        unsigned idx = atomicAdd(cnt, add);
        if (idx < LIST_CAP) {
          keys[idx] = (unsigned)((b * NS + n) * NS + m);
          vals[idx] = adj;
        }
        if (!diagTile && (idx + 1u) < LIST_CAP) {
          keys[idx + 1u] = (unsigned)((b * NS + m) * NS + n);
          vals[idx + 1u] = adj;
        }
      }
    }
  }
  if (!diagTile) { a2 *= 2.f; a3 *= 2.f; }

  // row sums: reduce across tx (16 lanes), write per row
  #pragma unroll
  for (int r = 0; r < 8; ++r) {
    float v = rowsum[r];
    v += __shfl_xor(v, 1, 64);
    v += __shfl_xor(v, 2, 64);
    v += __shfl_xor(v, 4, 64);
    v += __shfl_xor(v, 8, 64);
    rowsum[r] = v;
  }
  if (tx == 0) {
    #pragma unroll
    for (int r = 0; r < 8; ++r)
      rowp[tj * 16384 + b * NS + i0 + ty*4 + (r&3) + ((r>>2)<<6)] = rowsum[r];
  }

  // mirror col sums (rows of the tj tile, summed over ti cols)
  if (!diagTile) {
    #pragma unroll
    for (int c = 0; c < 8; ++c) {
      float v = colsum[c];
      v += __shfl_xor(v, 16, 64);
      v += __shfl_xor(v, 32, 64);
      colsum[c] = v;   // sum over this wave's 4 ty groups (32 rows)
    }
    __syncthreads();                       // done reading lsA; reuse as scratch
    int w = tid >> 6;
    if ((tid & 63) < 16) {
      #pragma unroll
      for (int c = 0; c < 8; ++c) lsA[w * 128 + tx * 8 + c] = colsum[c];
    }
    __syncthreads();
    if (tid < 128) {
      float v = lsA[tid] + lsA[128 + tid] + lsA[256 + tid] + lsA[384 + tid];
      int txx = tid >> 3, c8 = tid & 7;
      rowp[ti * 16384 + b * NS + j0 + txx*4 + (c8&3) + ((c8>>2)<<6)] = v;
    }
  }

  // A2/A3 block reduce (deterministic)
  float v2 = wave_sum(a2), v3 = wave_sum(a3);
  __syncthreads();
  if ((tid & 63) == 0) { sred[(tid >> 6)*2] = v2; sred[(tid >> 6)*2 + 1] = v3; }
  __syncthreads();
  if (tid == 0) {
    pA2[bid] = sred[0] + sred[2] + sred[4] + sred[6];
    pA3[bid] = sred[1] + sred[3] + sred[5] + sred[7];
  }
}

// K3: combine rowsum partials, compute 1/(row+eps), and A1 partials.
__global__ __launch_bounds__(256)
void k_rowcomb(const float* __restrict__ rowp, const float* __restrict__ nsq,
               float* __restrict__ rrow, float* __restrict__ pA1)
{
  __shared__ float red[256];
  int t = threadIdx.x;
  int g = blockIdx.x * 256 + t;
  float r = rowp[g] + rowp[16384 + g] + rowp[32768 + g] + rowp[49152 + g];
  rrow[g] = 1.f / (r + 1e-12f);
  red[t] = r * nsq[g];
  __syncthreads();
  for (int s = 128; s; s >>= 1) { if (t < s) red[t] += red[t + s]; __syncthreads(); }
  if (t == 0) pA1[blockIdx.x] = red[0];
}

// K4: M = diag * context  (diagonal part of adj@context)
__global__ __launch_bounds__(256)
void k_minit(const float* __restrict__ ctx, const float* __restrict__ diag,
             float* __restrict__ M)
{
  size_t fi = (size_t)blockIdx.x * 256 + threadIdx.x;   // f4 index
  int g = (int)(fi >> 6);
  float dv = diag[g];
  float4 v = ((const float4*)ctx)[fi];
  float4 o; o.x = v.x*dv; o.y = v.y*dv; o.z = v.z*dv; o.w = v.w*dv;
  ((float4*)M)[fi] = o;
}

// K4b: scatter rare off-diagonal adjacency contributions into M.
__global__ __launch_bounds__(256)
void k_scatter(const float* __restrict__ ctx, const unsigned* __restrict__ keys,
               const float* __restrict__ vals, const unsigned* __restrict__ cnt,
               float* __restrict__ M)
{
  unsigned c = *cnt; if (c > LIST_CAP) c = LIST_CAP;
  int t = threadIdx.x;
  for (unsigned e = blockIdx.x; e < c; e += gridDim.x) {
    unsigned key = keys[e];
    float v = vals[e];
    unsigned bn = key >> 9;                 // b*N+n
    unsigned m = key & 511u;
    unsigned bm = (bn & ~511u) | m;         // b*N+m
    atomicAdd(&M[(size_t)bn * ND + t], v * ctx[(size_t)bm * ND + t]);
  }
}

// K5/K6: out[16384,256] = act( (A .* rowscale?) @ W + bias )
template<bool RELU, bool SCALE>
__global__ __launch_bounds__(256, 2)
void k_lin(const float* __restrict__ A, const float* __restrict__ scale,
           const float* __restrict__ W, const float* __restrict__ bias,
           float* __restrict__ out)
{
  __shared__ float lsA[KC * LDP];
  __shared__ float lsB[KC * LDP];
  const int tid = threadIdx.x;
  const int tx = tid & 15, ty = tid >> 4;
  const int i0 = blockIdx.x * 128;          // rows (of 16384)
  const int col0 = blockIdx.y * 128;        // cols (of 256)

  float acc[8][8] = {};
  for (int kc = 0; kc < ND; kc += KC) {
    __syncthreads();
    #pragma unroll
    for (int q = 0; q < 4; ++q) {
      int f4 = q * 256 + tid;
      int row = f4 >> 3, k4 = f4 & 7;
      float4 v = ((const float4*)A)[(size_t)(i0 + row) * 64 + (kc >> 2) + k4];
      float s = SCALE ? scale[i0 + row] : 1.f;
      lsA[(k4*4+0)*LDP + row] = v.x * s;
      lsA[(k4*4+1)*LDP + row] = v.y * s;
      lsA[(k4*4+2)*LDP + row] = v.z * s;
      lsA[(k4*4+3)*LDP + row] = v.w * s;
      int kk = f4 >> 5, c4 = f4 & 31;
      float4 wv = ((const float4*)W)[(size_t)(kc + kk) * 64 + (col0 >> 2) + c4];
      *(float4*)(lsB + kk * LDP + c4 * 4) = wv;
    }
    __syncthreads();
    #pragma unroll
    for (int k = 0; k < KC; ++k) {
      const float* pa = lsA + k * LDP + ty * 4;
      const float* pb = lsB + k * LDP + tx * 4;
      float4 a0 = *(const float4*)(pa);
      float4 a1 = *(const float4*)(pa + 64);
      float4 b0 = *(const float4*)(pb);
      float4 b1 = *(const float4*)(pb + 64);
      float ar[8] = {a0.x,a0.y,a0.z,a0.w,a1.x,a1.y,a1.z,a1.w};
      float br[8] = {b0.x,b0.y,b0.z,b0.w,b1.x,b1.y,b1.z,b1.w};
      #pragma unroll
      for (int r = 0; r < 8; ++r)
        #pragma unroll
        for (int c = 0; c < 8; ++c)
          acc[r][c] = fmaf(ar[r], br[c], acc[r][c]);
    }
  }
  #pragma unroll
  for (int r = 0; r < 8; ++r) {
    int grow = i0 + ty*4 + (r&3) + ((r>>2)<<6);
    #pragma unroll
    for (int jj = 0; jj < 2; ++jj) {
      int colbase = col0 + tx*4 + (jj << 6);
      float4 bb = ((const float4*)bias)[colbase >> 2];
      float4 o;
      o.x = acc[r][jj*4+0] + bb.x;
      o.y = acc[r][jj*4+1] + bb.y;
      o.z = acc[r][jj*4+2] + bb.z;
      o.w = acc[r][jj*4+3] + bb.w;
      if (RELU) {
        o.x = fmaxf(o.x, 0.f); o.y = fmaxf(o.y, 0.f);
        o.z = fmaxf(o.z, 0.f); o.w = fmaxf(o.w, 0.f);
      }
      ((float4*)(out + (size_t)grow * ND))[colbase >> 2] = o;
    }
  }
}

// K7: per-row LayerNorm -> exact GELU -> dot with W_att2 -> wl
__global__ __launch_bounds__(256)
void k_ln(const float* __restrict__ a, const float* __restrict__ g,
          const float* __restrict__ bt, const float* __restrict__ W2,
          const float* __restrict__ b2, float* __restrict__ wl)
{
  int w = threadIdx.x >> 6, lane = threadIdx.x & 63;
  int row = blockIdx.x * 4 + w;
  float4 x = ((const float4*)a)[(size_t)row * 64 + lane];
  float s = x.x + x.y + x.z + x.w;
  float ss = fmaf(x.x, x.x, fmaf(x.y, x.y, fmaf(x.z, x.z, x.w * x.w)));
  s = wave_sum(s); ss = wave_sum(ss);
  float mu = s * (1.f / 256.f);
  float var = ss * (1.f / 256.f) - mu * mu;
  float rstd = rsqrtf(fmaxf(var, 0.f) + 1e-5f);
  float4 gg = ((const float4*)g)[lane];
  float4 bb = ((const float4*)bt)[lane];
  float4 wv = ((const float4*)W2)[lane];
  const float inv_sqrt2 = 0.70710678118654752f;
  float d = 0.f;
  {
    float y = (x.x - mu) * rstd * gg.x + bb.x;
    d = fmaf(0.5f * y * (1.f + erff(y * inv_sqrt2)), wv.x, d);
    y = (x.y - mu) * rstd * gg.y + bb.y;
    d = fmaf(0.5f * y * (1.f + erff(y * inv_sqrt2)), wv.y, d);
    y = (x.z - mu) * rstd * gg.z + bb.z;
    d = fmaf(0.5f * y * (1.f + erff(y * inv_sqrt2)), wv.z, d);
    y = (x.w - mu) * rstd * gg.w + bb.w;
    d = fmaf(0.5f * y * (1.f + erff(y * inv_sqrt2)), wv.w, d);
  }
  d = wave_sum(d);
  if (lane == 0) wl[row] = d + b2[0];
}

// K8: per-batch masked softmax over N, weighted pool of h, logits.
__global__ __launch_bounds__(256)
void k_pool(const float* __restrict__ wl, const int* __restrict__ amask,
            const float* __restrict__ h, const float* __restrict__ W_out,
            const float* __restrict__ b_out, float* __restrict__ out)
{
  __shared__ float sw[512];
  __shared__ float red[512];
  int b = blockIdx.x, t = threadIdx.x;
  float l0 = (amask[b * NS + t]       == 0) ? -INFINITY : wl[b * NS + t];
  float l1 = (amask[b * NS + 256 + t] == 0) ? -INFINITY : wl[b * NS + 256 + t];
  red[t] = fmaxf(l0, l1);
  __syncthreads();
  for (int s = 128; s; s >>= 1) { if (t < s) red[t] = fmaxf(red[t], red[t + s]); __syncthreads(); }
  float mx = red[0];
  __syncthreads();
  float e0 = expf(l0 - mx), e1 = expf(l1 - mx);
  red[t] = e0 + e1;
  __syncthreads();
  for (int s = 128; s; s >>= 1) { if (t < s) red[t] += red[t + s]; __syncthreads(); }
  float inv = 1.f / red[0];
  __syncthreads();
  sw[t] = e0 * inv; sw[256 + t] = e1 * inv;
  __syncthreads();
  float acc = 0.f;
  const float* hb = h + (size_t)b * NS * ND;
  for (int n = 0; n < NS; ++n) acc = fmaf(sw[n], hb[(size_t)n * ND + t], acc);
  red[t]       = acc * W_out[t * 2 + 0];
  red[256 + t] = acc * W_out[t * 2 + 1];
  __syncthreads();
  for (int s = 128; s; s >>= 1) {
    if (t < s) { red[t] += red[t + s]; red[256 + t] += red[256 + t + s]; }
    __syncthreads();
  }
  if (t == 0) {
    out[b * 2 + 0] = red[0]   + b_out[0];
    out[b * 2 + 1] = red[256] + b_out[1];
  }
}

// K9: final graph loss scalar (deterministic tree over partials)
__global__ __launch_bounds__(256)
void k_loss(const float* __restrict__ pA1, const float* __restrict__ pA2,
            const float* __restrict__ pA3, float* __restrict__ out)
{
  __shared__ float r1[256], r2[256], r3[256];
  int t = threadIdx.x;
  r1[t] = (t < 64) ? pA1[t] : 0.f;
  r2[t] = pA2[t] + pA2[t + 256];
  r3[t] = pA3[t] + pA3[t + 256];
  __syncthreads();
  for (int s = 128; s; s >>= 1) {
    if (t < s) { r1[t] += r1[t + s]; r2[t] += r2[t + s]; r3[t] += r3[t + s]; }
    __syncthreads();
  }
  if (t == 0) {
    float smooth = 0.2f * (r1[0] - r2[0]) * (1.f / (32.f * 512.f * 512.f));
    float spars  = 0.1f * r3[0] * (1.f / (512.f * 512.f)) * (1.f / 32.f);
    out[64] = smooth + spars;
  }
}

extern "C" void kernel_launch(void* const* d_in, const int* in_sizes, int n_in,
                              void* d_out, int out_size, void* d_ws, size_t ws_size,
                              hipStream_t stream)
{
  (void)in_sizes; (void)n_in; (void)out_size; (void)ws_size;
  const float* ctx    = (const float*)d_in[0];
  const int*   amask  = (const int*)d_in[1];
  const float* W_gcn  = (const float*)d_in[2];
  const float* b_gcn  = (const float*)d_in[3];
  const float* W_att1 = (const float*)d_in[4];
  const float* b_att1 = (const float*)d_in[5];
  const float* ln_g   = (const float*)d_in[6];
  const float* ln_b   = (const float*)d_in[7];
  const float* W_att2 = (const float*)d_in[8];
  const float* b_att2 = (const float*)d_in[9];
  const float* W_out  = (const float*)d_in[10];
  const float* b_out  = (const float*)d_in[11];
  float* out = (float*)d_out;

  float* ws   = (float*)d_ws;
  float* M    = ws;                 // B*N*D ; reused as 'a' after K5
  float* h    = M + 4194304;        // B*N*H
  float* nrm  = h + 4194304;
  float* nsq  = nrm + 16384;
  float* rnrm = nsq + 16384;
  float* rowp = rnrm + 16384;       // 4*16384
  float* rrow = rowp + 65536;
  float* diag = rrow + 16384;
  float* wl   = diag + 16384;
  float* pA1  = wl + 16384;         // 64
  float* pA2  = pA1 + 64;           // 512
  float* pA3  = pA2 + 512;          // 512
  unsigned* cnt  = (unsigned*)(pA3 + 512);
  unsigned* keys = cnt + 1;         // 32768
  float* vals = (float*)(keys + 32768);

  k_norm<<<4096, 256, 0, stream>>>(ctx, nrm, nsq, rnrm, cnt);
  k_gram<<<dim3(4, 4, 32), 256, 0, stream>>>(ctx, nrm, rnrm, rowp, diag,
                                             pA2, pA3, cnt, keys, vals);
  k_rowcomb<<<64, 256, 0, stream>>>(rowp, nsq, rrow, pA1);
  k_minit<<<4096, 256, 0, stream>>>(ctx, diag, M);
  k_scatter<<<64, 256, 0, stream>>>(ctx, keys, vals, cnt, M);
  k_lin<true, true><<<dim3(128, 2), 256, 0, stream>>>(M, rrow, W_gcn, b_gcn, h);
  k_lin<false, false><<<dim3(128, 2), 256, 0, stream>>>(h, nullptr, W_att1, b_att1, M);
  k_ln<<<4096, 256, 0, stream>>>(M, ln_g, ln_b, W_att2, b_att2, wl);
  k_pool<<<32, 256, 0, stream>>>(wl, amask, h, W_out, b_out, out);
  k_loss<<<1, 256, 0, stream>>>(pA1, pA2, pA3, out);
}

// Round 2
// 147.055 us; speedup vs baseline: 1.2773x; 1.2773x over previous
//
#include <hip/hip_runtime.h>
#include <math.h>

#define NS 512
#define ND 256
#define LIST_CAP 32768u

typedef short short8 __attribute__((ext_vector_type(8)));
typedef float f32x16 __attribute__((ext_vector_type(16)));

__device__ __forceinline__ unsigned short bf16_rne(float x) {
  unsigned u = __float_as_uint(x);
  unsigned r = u + 0x7fffu + ((u >> 16) & 1u);
  return (unsigned short)(r >> 16);
}
__device__ __forceinline__ float bf16_tof(unsigned short h) {
  return __uint_as_float(((unsigned)h) << 16);
}
__device__ __forceinline__ void bsplit(float x, unsigned short& h, unsigned short& l) {
  h = bf16_rne(x);
  l = bf16_rne(x - bf16_tof(h));
}
__device__ __forceinline__ float wave_sum(float v) {
  v += __shfl_xor(v, 1);  v += __shfl_xor(v, 2);  v += __shfl_xor(v, 4);
  v += __shfl_xor(v, 8);  v += __shfl_xor(v, 16); v += __shfl_xor(v, 32);
  return v;
}

// K1: norms + normalized bf16 split of context; zero sparse counter.
__global__ __launch_bounds__(256)
void k_prep(const float* __restrict__ ctx, float* __restrict__ nrm,
            float* __restrict__ nsq, float* __restrict__ rnrm,
            unsigned short* __restrict__ cnhi, unsigned short* __restrict__ cnlo,
            unsigned* __restrict__ cnt)
{
  if (blockIdx.x == 0 && threadIdx.x == 0) *cnt = 0u;
  int w = threadIdx.x >> 6, lane = threadIdx.x & 63;
  int g = blockIdx.x * 4 + w;
  float4 v = ((const float4*)ctx)[(size_t)g * 64 + lane];
  float ss = v.x*v.x + v.y*v.y + v.z*v.z + v.w*v.w;
  ss = wave_sum(ss);
  float n = sqrtf(ss);
  float rn = 1.f / fmaxf(n, 1e-12f);
  if (lane == 0) { nrm[g] = n; nsq[g] = ss; rnrm[g] = rn; }
  ushort4 hi, lo;
  bsplit(v.x * rn, hi.x, lo.x);
  bsplit(v.y * rn, hi.y, lo.y);
  bsplit(v.z * rn, hi.z, lo.z);
  bsplit(v.w * rn, hi.w, lo.w);
  ((ushort4*)cnhi)[(size_t)g * 64 + lane] = hi;
  ((ushort4*)cnlo)[(size_t)g * 64 + lane] = lo;
}

// K2: transpose + split both weight matrices (256x256 each). blockIdx.y picks which.
__global__ __launch_bounds__(256)
void k_prepW(const float* __restrict__ Wg, const float* __restrict__ Wa,
             unsigned short* __restrict__ wgthi, unsigned short* __restrict__ wgtlo,
             unsigned short* __restrict__ wathi, unsigned short* __restrict__ watlo)
{
  int j = blockIdx.x, k = threadIdx.x;
  const float* W = blockIdx.y ? Wa : Wg;
  unsigned short h, l;
  bsplit(W[k * ND + j], h, l);
  if (blockIdx.y) { wathi[j * ND + k] = h; watlo[j * ND + k] = l; }
  else            { wgthi[j * ND + k] = h; wgtlo[j * ND + k] = l; }
}

// K3: gram via split-bf16 MFMA, 128x128 tile per block, waves 2x2 of 64x64.
// Frags loaded straight from global (L2-resident); epilogue does threshold,
// row/col sums, diag, A2/A3, sparse push.
__global__ __launch_bounds__(256)
void k_gram2(const unsigned short* __restrict__ cnhi, const unsigned short* __restrict__ cnlo,
             const float* __restrict__ nrm,
             float* __restrict__ rowp, float* __restrict__ diag,
             float* __restrict__ pA2, float* __restrict__ pA3,
             unsigned* __restrict__ cnt, unsigned* __restrict__ keys,
             float* __restrict__ vals)
{
  __shared__ float s_row[2][128];
  __shared__ float s_col[2][128];
  __shared__ float sred[8];
  const int bx = blockIdx.x;
  const int b = bx / 10, p = bx % 10;
  const int ti = (p < 4) ? 0 : (p < 7) ? 1 : (p < 9) ? 2 : 3;
  const int tj = p - ((ti == 0) ? 0 : (ti == 1) ? 3 : (ti == 2) ? 5 : 6);
  const bool diagT = (ti == tj);
  const int i0 = ti * 128, j0 = tj * 128;
  const int bB = b * NS;
  const int rbA = bB + i0, rbB = bB + j0;

  const int tid = threadIdx.x;
  const int lane = tid & 63, wid = tid >> 6;
  const int l31 = lane & 31, hl = lane >> 5;
  const int wr = wid >> 1, wc = wid & 1;

  const size_t offA = (size_t)(rbA + wr * 64 + l31) * ND + hl * 8;
  const size_t offB = (size_t)(rbB + wc * 64 + l31) * ND + hl * 8;
  const unsigned short* pAh = cnhi + offA;
  const unsigned short* pAl = cnlo + offA;
  const unsigned short* pBh = cnhi + offB;
  const unsigned short* pBl = cnlo + offB;

  f32x16 acc[2][2] = {};
  for (int kc = 0; kc < ND; kc += 16) {
    short8 ah[2], al[2], bh[2], bl[2];
    #pragma unroll
    for (int s = 0; s < 2; ++s) {
      ah[s] = *(const short8*)(pAh + s * 32 * ND + kc);
      al[s] = *(const short8*)(pAl + s * 32 * ND + kc);
      bh[s] = *(const short8*)(pBh + s * 32 * ND + kc);
      bl[s] = *(const short8*)(pBl + s * 32 * ND + kc);
    }
    #pragma unroll
    for (int sr = 0; sr < 2; ++sr)
      #pragma unroll
      for (int sc = 0; sc < 2; ++sc) {
        acc[sr][sc] = __builtin_amdgcn_mfma_f32_32x32x16_bf16(ah[sr], bh[sc], acc[sr][sc], 0, 0, 0);
        acc[sr][sc] = __builtin_amdgcn_mfma_f32_32x32x16_bf16(ah[sr], bl[sc], acc[sr][sc], 0, 0, 0);
        acc[sr][sc] = __builtin_amdgcn_mfma_f32_32x32x16_bf16(al[sr], bh[sc], acc[sr][sc], 0, 0, 0);
      }
  }

  // ---- epilogue ----
  const float nc0 = nrm[rbB + wc * 64 + l31];
  const float nc1 = nrm[rbB + wc * 64 + 32 + l31];
  float a2 = 0.f, a3 = 0.f, colsum0 = 0.f, colsum1 = 0.f;

  #pragma unroll
  for (int sr = 0; sr < 2; ++sr) {
    #pragma unroll
    for (int r = 0; r < 16; ++r) {
      const int rofs = (r & 3) + 8 * (r >> 2) + 4 * hl;
      const int grow = wr * 64 + sr * 32 + rofs;          // local row 0..127
      const float nr = nrm[rbA + grow];
      float rs = 0.f;
      #pragma unroll
      for (int sc = 0; sc < 2; ++sc) {
        float v = acc[sr][sc][r];
        float adj = (v > 0.3f) ? v : 0.f;
        float q2 = adj * adj;
        a3 += q2;
        a2 += q2 * nr * ((sc == 0) ? nc0 : nc1);
        rs += adj;
        if (sc == 0) colsum0 += adj; else colsum1 += adj;
        int gcol = wc * 64 + sc * 32 + l31;               // local col 0..127
        if (diagT) {
          if (grow == gcol) {
            diag[bB + i0 + grow] = adj;
          } else if (adj > 0.f) {
            unsigned idx = atomicAdd(cnt, 1u);
            if (idx < LIST_CAP) {
              keys[idx] = (unsigned)((bB + i0 + grow) * NS + (j0 + gcol));
              vals[idx] = adj;
            }
          }
        } else if (adj > 0.f) {
          unsigned idx = atomicAdd(cnt, 2u);
          if (idx < LIST_CAP) {
            keys[idx] = (unsigned)((bB + i0 + grow) * NS + (j0 + gcol));
            vals[idx] = adj;
          }
          if (idx + 1u < LIST_CAP) {
            keys[idx + 1u] = (unsigned)((bB + j0 + gcol) * NS + (i0 + grow));
            vals[idx + 1u] = adj;
          }
        }
      }
      rs += __shfl_xor(rs, 1); rs += __shfl_xor(rs, 2); rs += __shfl_xor(rs, 4);
      rs += __shfl_xor(rs, 8); rs += __shfl_xor(rs, 16);
      if (l31 == 0) s_row[wc][grow] = rs;
    }
  }
  colsum0 += __shfl_xor(colsum0, 32);
  colsum1 += __shfl_xor(colsum1, 32);
  if (!diagT && hl == 0) {
    s_col[wr][wc * 64 + l31] = colsum0;
    s_col[wr][wc * 64 + 32 + l31] = colsum1;
  }
  a2 = wave_sum(a2);
  a3 = wave_sum(a3);
  if (lane == 0) { sred[wid] = a2; sred[4 + wid] = a3; }
  __syncthreads();
  if (tid < 128) {
    rowp[tj * 16384 + rbA + tid] = s_row[0][tid] + s_row[1][tid];
    if (!diagT)
      rowp[ti * 16384 + rbB + tid] = s_col[0][tid] + s_col[1][tid];
  }
  if (tid == 0) {
    float f = diagT ? 1.f : 2.f;
    pA2[bx] = f * (sred[0] + sred[1] + sred[2] + sred[3]);
    pA3[bx] = f * (sred[4] + sred[5] + sred[6] + sred[7]);
  }
}

// K4: combine rowsum partials -> rrow, A1 partials.
__global__ __launch_bounds__(256)
void k_rowcomb(const float* __restrict__ rowp, const float* __restrict__ nsq,
               float* __restrict__ rrow, float* __restrict__ pA1)
{
  __shared__ float red[256];
  int t = threadIdx.x;
  int g = blockIdx.x * 256 + t;
  float r = rowp[g] + rowp[16384 + g] + rowp[32768 + g] + rowp[49152 + g];
  rrow[g] = 1.f / (r + 1e-12f);
  red[t] = r * nsq[g];
  __syncthreads();
  for (int s = 128; s; s >>= 1) { if (t < s) red[t] += red[t + s]; __syncthreads(); }
  if (t == 0) pA1[blockIdx.x] = red[0];
}

// K5: Mscaled = rrow * diag * ctx  -> bf16 hi/lo (diagonal part of adj_norm@ctx).
__global__ __launch_bounds__(256)
void k_minit2(const float* __restrict__ ctx, const float* __restrict__ diag,
              const float* __restrict__ rrow,
              unsigned short* __restrict__ Mhi, unsigned short* __restrict__ Mlo)
{
  size_t fi = (size_t)blockIdx.x * 256 + threadIdx.x;
  int g = (int)(fi >> 6);
  float s = diag[g] * rrow[g];
  float4 v = ((const float4*)ctx)[fi];
  ushort4 hi, lo;
  bsplit(v.x * s, hi.x, lo.x);
  bsplit(v.y * s, hi.y, lo.y);
  bsplit(v.z * s, hi.z, lo.z);
  bsplit(v.w * s, hi.w, lo.w);
  ((ushort4*)Mhi)[fi] = hi;
  ((ushort4*)Mlo)[fi] = lo;
}

// K6: serial fixup of the rare off-diagonal adjacency entries (one block).
__global__ __launch_bounds__(256)
void k_scatter2(const float* __restrict__ ctx, const unsigned* __restrict__ keys,
                const float* __restrict__ vals, const unsigned* __restrict__ cnt,
                const float* __restrict__ rrow,
                unsigned short* __restrict__ Mhi, unsigned short* __restrict__ Mlo)
{
  unsigned c = *cnt; if (c > LIST_CAP) c = LIST_CAP;
  int t = threadIdx.x;
  for (unsigned e = 0; e < c; ++e) {
    unsigned key = keys[e];
    float v = vals[e];
    unsigned bn = key >> 9;
    unsigned m = key & 511u;
    unsigned bm = (bn & ~511u) | m;
    size_t idx = (size_t)bn * ND + t;
    float old = bf16_tof(Mhi[idx]) + bf16_tof(Mlo[idx]);
    float nv = old + v * rrow[bn] * ctx[(size_t)bm * ND + t];
    unsigned short h, l;
    bsplit(nv, h, l);
    Mhi[idx] = h; Mlo[idx] = l;
  }
}

// K7: C[16384,256] = act(A @ W + bias) via split-bf16 MFMA; Wt pre-transposed.
// MODE 0: relu, write fp32 + bf16 split. MODE 1: write fp32 only.
template<int MODE>
__global__ __launch_bounds__(256)
void k_mm(const unsigned short* __restrict__ Ahi, const unsigned short* __restrict__ Alo,
          const unsigned short* __restrict__ Bthi, const unsigned short* __restrict__ Btlo,
          const float* __restrict__ bias, float* __restrict__ outf,
          unsigned short* __restrict__ Ohi, unsigned short* __restrict__ Olo)
{
  const int i0 = blockIdx.x * 128;
  const int c0 = blockIdx.y * 128;
  const int tid = threadIdx.x;
  const int lane = tid & 63, wid = tid >> 6;
  const int l31 = lane & 31, hl = lane >> 5;
  const int wr = wid >> 1, wc = wid & 1;

  const size_t offA = (size_t)(i0 + wr * 64 + l31) * ND + hl * 8;
  const size_t offB = (size_t)(c0 + wc * 64 + l31) * ND + hl * 8;
  const unsigned short* pAh = Ahi + offA;
  const unsigned short* pAl = Alo + offA;
  const unsigned short* pBh = Bthi + offB;
  const unsigned short* pBl = Btlo + offB;

  f32x16 acc[2][2] = {};
  for (int kc = 0; kc < ND; kc += 16) {
    short8 ah[2], al[2], bh[2], bl[2];
    #pragma unroll
    for (int s = 0; s < 2; ++s) {
      ah[s] = *(const short8*)(pAh + s * 32 * ND + kc);
      al[s] = *(const short8*)(pAl + s * 32 * ND + kc);
      bh[s] = *(const short8*)(pBh + s * 32 * ND + kc);
      bl[s] = *(const short8*)(pBl + s * 32 * ND + kc);
    }
    #pragma unroll
    for (int sr = 0; sr < 2; ++sr)
      #pragma unroll
      for (int sc = 0; sc < 2; ++sc) {
        acc[sr][sc] = __builtin_amdgcn_mfma_f32_32x32x16_bf16(ah[sr], bh[sc], acc[sr][sc], 0, 0, 0);
        acc[sr][sc] = __builtin_amdgcn_mfma_f32_32x32x16_bf16(ah[sr], bl[sc], acc[sr][sc], 0, 0, 0);
        acc[sr][sc] = __builtin_amdgcn_mfma_f32_32x32x16_bf16(al[sr], bh[sc], acc[sr][sc], 0, 0, 0);
      }
  }
  const float b0 = bias[c0 + wc * 64 + l31];
  const float b1 = bias[c0 + wc * 64 + 32 + l31];
  #pragma unroll
  for (int sr = 0; sr < 2; ++sr) {
    #pragma unroll
    for (int r = 0; r < 16; ++r) {
      const int rofs = (r & 3) + 8 * (r >> 2) + 4 * hl;
      const size_t grow = (size_t)(i0 + wr * 64 + sr * 32 + rofs);
      #pragma unroll
      for (int sc = 0; sc < 2; ++sc) {
        int gcol = c0 + wc * 64 + sc * 32 + l31;
        float v = acc[sr][sc][r] + ((sc == 0) ? b0 : b1);
        if (MODE == 0) v = fmaxf(v, 0.f);
        outf[grow * ND + gcol] = v;
        if (MODE == 0) {
          unsigned short h, l;
          bsplit(v, h, l);
          Ohi[grow * ND + gcol] = h;
          Olo[grow * ND + gcol] = l;
        }
      }
    }
  }
}

// K8: per-row LayerNorm -> exact GELU -> dot with W_att2 -> wl
__global__ __launch_bounds__(256)
void k_ln(const float* __restrict__ a, const float* __restrict__ g,
          const float* __restrict__ bt, const float* __restrict__ W2,
          const float* __restrict__ b2, float* __restrict__ wl)
{
  int w = threadIdx.x >> 6, lane = threadIdx.x & 63;
  int row = blockIdx.x * 4 + w;
  float4 x = ((const float4*)a)[(size_t)row * 64 + lane];
  float s = x.x + x.y + x.z + x.w;
  float ss = fmaf(x.x, x.x, fmaf(x.y, x.y, fmaf(x.z, x.z, x.w * x.w)));
  s = wave_sum(s); ss = wave_sum(ss);
  float mu = s * (1.f / 256.f);
  float var = ss * (1.f / 256.f) - mu * mu;
  float rstd = rsqrtf(fmaxf(var, 0.f) + 1e-5f);
  float4 gg = ((const float4*)g)[lane];
  float4 bb = ((const float4*)bt)[lane];
  float4 wv = ((const float4*)W2)[lane];
  const float inv_sqrt2 = 0.70710678118654752f;
  float d = 0.f;
  float y = (x.x - mu) * rstd * gg.x + bb.x;
  d = fmaf(0.5f * y * (1.f + erff(y * inv_sqrt2)), wv.x, d);
  y = (x.y - mu) * rstd * gg.y + bb.y;
  d = fmaf(0.5f * y * (1.f + erff(y * inv_sqrt2)), wv.y, d);
  y = (x.z - mu) * rstd * gg.z + bb.z;
  d = fmaf(0.5f * y * (1.f + erff(y * inv_sqrt2)), wv.z, d);
  y = (x.w - mu) * rstd * gg.w + bb.w;
  d = fmaf(0.5f * y * (1.f + erff(y * inv_sqrt2)), wv.w, d);
  d = wave_sum(d);
  if (lane == 0) wl[row] = d + b2[0];
}

// K9: per-batch masked softmax over N, weighted pool of h, logits.
__global__ __launch_bounds__(256)
void k_pool(const float* __restrict__ wl, const int* __restrict__ amask,
            const float* __restrict__ h, const float* __restrict__ W_out,
            const float* __restrict__ b_out, float* __restrict__ out)
{
  __shared__ float sw[512];
  __shared__ float red[512];
  int b = blockIdx.x, t = threadIdx.x;
  float l0 = (amask[b * NS + t]       == 0) ? -INFINITY : wl[b * NS + t];
  float l1 = (amask[b * NS + 256 + t] == 0) ? -INFINITY : wl[b * NS + 256 + t];
  red[t] = fmaxf(l0, l1);
  __syncthreads();
  for (int s = 128; s; s >>= 1) { if (t < s) red[t] = fmaxf(red[t], red[t + s]); __syncthreads(); }
  float mx = red[0];
  __syncthreads();
  float e0 = expf(l0 - mx), e1 = expf(l1 - mx);
  red[t] = e0 + e1;
  __syncthreads();
  for (int s = 128; s; s >>= 1) { if (t < s) red[t] += red[t + s]; __syncthreads(); }
  float inv = 1.f / red[0];
  __syncthreads();
  sw[t] = e0 * inv; sw[256 + t] = e1 * inv;
  __syncthreads();
  float acc = 0.f;
  const float* hb = h + (size_t)b * NS * ND;
  #pragma unroll 8
  for (int n = 0; n < NS; ++n) acc = fmaf(sw[n], hb[(size_t)n * ND + t], acc);
  red[t]       = acc * W_out[t * 2 + 0];
  red[256 + t] = acc * W_out[t * 2 + 1];
  __syncthreads();
  for (int s = 128; s; s >>= 1) {
    if (t < s) { red[t] += red[t + s]; red[256 + t] += red[256 + t + s]; }
    __syncthreads();
  }
  if (t == 0) {
    out[b * 2 + 0] = red[0]   + b_out[0];
    out[b * 2 + 1] = red[256] + b_out[1];
  }
}

// K10: final graph loss scalar (pA2/pA3 have 320 entries).
__global__ __launch_bounds__(256)
void k_loss(const float* __restrict__ pA1, const float* __restrict__ pA2,
            const float* __restrict__ pA3, float* __restrict__ out)
{
  __shared__ float r1[256], r2[256], r3[256];
  int t = threadIdx.x;
  r1[t] = (t < 64) ? pA1[t] : 0.f;
  r2[t] = pA2[t] + ((t < 64) ? pA2[256 + t] : 0.f);
  r3[t] = pA3[t] + ((t < 64) ? pA3[256 + t] : 0.f);
  __syncthreads();
  for (int s = 128; s; s >>= 1) {
    if (t < s) { r1[t] += r1[t + s]; r2[t] += r2[t + s]; r3[t] += r3[t + s]; }
    __syncthreads();
  }
  if (t == 0) {
    float smooth = 0.2f * (r1[0] - r2[0]) * (1.f / (32.f * 512.f * 512.f));
    float spars  = 0.1f * r3[0] * (1.f / (512.f * 512.f)) * (1.f / 32.f);
    out[64] = smooth + spars;
  }
}

extern "C" void kernel_launch(void* const* d_in, const int* in_sizes, int n_in,
                              void* d_out, int out_size, void* d_ws, size_t ws_size,
                              hipStream_t stream)
{
  (void)in_sizes; (void)n_in; (void)out_size; (void)ws_size;
  const float* ctx    = (const float*)d_in[0];
  const int*   amask  = (const int*)d_in[1];
  const float* W_gcn  = (const float*)d_in[2];
  const float* b_gcn  = (const float*)d_in[3];
  const float* W_att1 = (const float*)d_in[4];
  const float* b_att1 = (const float*)d_in[5];
  const float* ln_g   = (const float*)d_in[6];
  const float* ln_b   = (const float*)d_in[7];
  const float* W_att2 = (const float*)d_in[8];
  const float* b_att2 = (const float*)d_in[9];
  const float* W_out  = (const float*)d_in[10];
  const float* b_out  = (const float*)d_in[11];
  float* out = (float*)d_out;

  float* ws = (float*)d_ws;
  // W0 (16.8 MB): cn hi/lo, later reused as h hi/lo
  unsigned short* cnhi = (unsigned short*)ws;
  unsigned short* cnlo = (unsigned short*)(ws + 2097152);
  unsigned short* hhi  = cnhi;
  unsigned short* hlo  = cnlo;
  // W1 (16.8 MB): h fp32
  float* hbuf = ws + 4194304;
  // W2 (16.8 MB): M hi/lo, later reused as 'a' fp32
  unsigned short* Mhi = (unsigned short*)(ws + 8388608);
  unsigned short* Mlo = (unsigned short*)(ws + 8388608 + 2097152);
  float* abuf = ws + 8388608;
  // small region
  float* sp   = ws + 12582912;
  float* nrm  = sp;            sp += 16384;
  float* nsq  = sp;            sp += 16384;
  float* rnrm = sp;            sp += 16384;
  float* rowp = sp;            sp += 65536;
  float* rrow = sp;            sp += 16384;
  float* diag = sp;            sp += 16384;
  float* wl   = sp;            sp += 16384;
  float* pA1  = sp;            sp += 64;
  float* pA2  = sp;            sp += 320;
  float* pA3  = sp;            sp += 320;
  unsigned* cnt  = (unsigned*)sp;  sp += 64;
  unsigned* keys = (unsigned*)sp;  sp += 32768;
  float* vals = sp;            sp += 32768;
  unsigned short* wgthi = (unsigned short*)sp; sp += 32768;
  unsigned short* wgtlo = (unsigned short*)sp; sp += 32768;
  unsigned short* wathi = (unsigned short*)sp; sp += 32768;
  unsigned short* watlo = (unsigned short*)sp; sp += 32768;

  k_prep<<<4096, 256, 0, stream>>>(ctx, nrm, nsq, rnrm, cnhi, cnlo, cnt);
  k_prepW<<<dim3(256, 2), 256, 0, stream>>>(W_gcn, W_att1, wgthi, wgtlo, wathi, watlo);
  k_gram2<<<320, 256, 0, stream>>>(cnhi, cnlo, nrm, rowp, diag, pA2, pA3, cnt, keys, vals);
  k_rowcomb<<<64, 256, 0, stream>>>(rowp, nsq, rrow, pA1);
  k_minit2<<<4096, 256, 0, stream>>>(ctx, diag, rrow, Mhi, Mlo);
  k_scatter2<<<1, 256, 0, stream>>>(ctx, keys, vals, cnt, rrow, Mhi, Mlo);
  k_mm<0><<<dim3(128, 2), 256, 0, stream>>>(Mhi, Mlo, wgthi, wgtlo, b_gcn, hbuf, hhi, hlo);
  k_mm<1><<<dim3(128, 2), 256, 0, stream>>>(hhi, hlo, wathi, watlo, b_att1, abuf, nullptr, nullptr);
  k_ln<<<4096, 256, 0, stream>>>(abuf, ln_g, ln_b, W_att2, b_att2, wl);
  k_pool<<<32, 256, 0, stream>>>(wl, amask, hbuf, W_out, b_out, out);
  k_loss<<<1, 256, 0, stream>>>(pA1, pA2, pA3, out);
}

// Round 3
// 128.097 us; speedup vs baseline: 1.4664x; 1.1480x over previous
//
#include <hip/hip_runtime.h>
#include <math.h>

#define NS 512
#define ND 256
#define LIST_CAP 32768u

typedef short short8 __attribute__((ext_vector_type(8)));
typedef float f32x16 __attribute__((ext_vector_type(16)));

__device__ __forceinline__ unsigned short bf16_rne(float x) {
  unsigned u = __float_as_uint(x);
  unsigned r = u + 0x7fffu + ((u >> 16) & 1u);
  return (unsigned short)(r >> 16);
}
__device__ __forceinline__ float bf16_tof(unsigned short h) {
  return __uint_as_float(((unsigned)h) << 16);
}
__device__ __forceinline__ void bsplit(float x, unsigned short& h, unsigned short& l) {
  h = bf16_rne(x);
  l = bf16_rne(x - bf16_tof(h));
}
__device__ __forceinline__ float wave_sum(float v) {
  v += __shfl_xor(v, 1);  v += __shfl_xor(v, 2);  v += __shfl_xor(v, 4);
  v += __shfl_xor(v, 8);  v += __shfl_xor(v, 16); v += __shfl_xor(v, 32);
  return v;
}

// 8 operand fragments for one kc step: A hi (2 slices), A lo, B hi, B lo
#define GLOADS(S, kc) do { \
  S[0] = *(const short8*)(pAh + (kc)); \
  S[1] = *(const short8*)(pAh + 32*ND + (kc)); \
  S[2] = *(const short8*)(pAl + (kc)); \
  S[3] = *(const short8*)(pAl + 32*ND + (kc)); \
  S[4] = *(const short8*)(pBh + (kc)); \
  S[5] = *(const short8*)(pBh + 32*ND + (kc)); \
  S[6] = *(const short8*)(pBl + (kc)); \
  S[7] = *(const short8*)(pBl + 32*ND + (kc)); \
} while (0)

// split-bf16: hi*hi + hi*lo + lo*hi into the same fp32 accumulators
#define GMFMA(S) do { \
  acc[0][0] = __builtin_amdgcn_mfma_f32_32x32x16_bf16(S[0], S[4], acc[0][0], 0, 0, 0); \
  acc[0][1] = __builtin_amdgcn_mfma_f32_32x32x16_bf16(S[0], S[5], acc[0][1], 0, 0, 0); \
  acc[1][0] = __builtin_amdgcn_mfma_f32_32x32x16_bf16(S[1], S[4], acc[1][0], 0, 0, 0); \
  acc[1][1] = __builtin_amdgcn_mfma_f32_32x32x16_bf16(S[1], S[5], acc[1][1], 0, 0, 0); \
  acc[0][0] = __builtin_amdgcn_mfma_f32_32x32x16_bf16(S[0], S[6], acc[0][0], 0, 0, 0); \
  acc[0][1] = __builtin_amdgcn_mfma_f32_32x32x16_bf16(S[0], S[7], acc[0][1], 0, 0, 0); \
  acc[1][0] = __builtin_amdgcn_mfma_f32_32x32x16_bf16(S[1], S[6], acc[1][0], 0, 0, 0); \
  acc[1][1] = __builtin_amdgcn_mfma_f32_32x32x16_bf16(S[1], S[7], acc[1][1], 0, 0, 0); \
  acc[0][0] = __builtin_amdgcn_mfma_f32_32x32x16_bf16(S[2], S[4], acc[0][0], 0, 0, 0); \
  acc[0][1] = __builtin_amdgcn_mfma_f32_32x32x16_bf16(S[2], S[5], acc[0][1], 0, 0, 0); \
  acc[1][0] = __builtin_amdgcn_mfma_f32_32x32x16_bf16(S[3], S[4], acc[1][0], 0, 0, 0); \
  acc[1][1] = __builtin_amdgcn_mfma_f32_32x32x16_bf16(S[3], S[5], acc[1][1], 0, 0, 0); \
} while (0)

// K1: norms + normalized bf16 split of context; fused weight transpose+split;
// zero sparse counter. Blocks 0..4095 handle ctx rows; 4096..4607 handle W cols.
__global__ __launch_bounds__(256)
void k_prep(const float* __restrict__ ctx, const float* __restrict__ Wg,
            const float* __restrict__ Wa,
            float* __restrict__ nrm, float* __restrict__ nsq,
            unsigned short* __restrict__ cnhi, unsigned short* __restrict__ cnlo,
            unsigned short* __restrict__ wgthi, unsigned short* __restrict__ wgtlo,
            unsigned short* __restrict__ wathi, unsigned short* __restrict__ watlo,
            unsigned* __restrict__ cnt)
{
  if (blockIdx.x >= 4096) {
    int wb = blockIdx.x - 4096;
    int j = wb & 255, selA = wb >> 8;
    int k = threadIdx.x;
    if (wb == 0 && k == 0) *cnt = 0u;
    const float* W = selA ? Wa : Wg;
    unsigned short h, l;
    bsplit(W[k * ND + j], h, l);
    if (selA) { wathi[j * ND + k] = h; watlo[j * ND + k] = l; }
    else      { wgthi[j * ND + k] = h; wgtlo[j * ND + k] = l; }
    return;
  }
  int w = threadIdx.x >> 6, lane = threadIdx.x & 63;
  int g = blockIdx.x * 4 + w;
  float4 v = ((const float4*)ctx)[(size_t)g * 64 + lane];
  float ss = v.x*v.x + v.y*v.y + v.z*v.z + v.w*v.w;
  ss = wave_sum(ss);
  float n = sqrtf(ss);
  float rn = 1.f / fmaxf(n, 1e-12f);
  if (lane == 0) { nrm[g] = n; nsq[g] = ss; }
  ushort4 hi, lo;
  bsplit(v.x * rn, hi.x, lo.x);
  bsplit(v.y * rn, hi.y, lo.y);
  bsplit(v.z * rn, hi.z, lo.z);
  bsplit(v.w * rn, hi.w, lo.w);
  ((ushort4*)cnhi)[(size_t)g * 64 + lane] = hi;
  ((ushort4*)cnlo)[(size_t)g * 64 + lane] = lo;
}

// K2: gram via split-bf16 MFMA, 128x128 tile per block, register-pipelined
// K loop (depth 3), XCD-swizzled block ids. Epilogue: threshold, row/col sums,
// diag, A2/A3 partials, sparse off-diagonal push.
__global__ __launch_bounds__(256, 2)
void k_gram2(const unsigned short* __restrict__ cnhi, const unsigned short* __restrict__ cnlo,
             const float* __restrict__ nrm,
             float* __restrict__ rowp, float* __restrict__ diag,
             float* __restrict__ pA2, float* __restrict__ pA3,
             unsigned* __restrict__ cnt, unsigned* __restrict__ keys,
             float* __restrict__ vals)
{
  __shared__ float s_row[2][128];
  __shared__ float s_col[2][128];
  __shared__ float sred[8];
  const int bx0 = blockIdx.x;
  const int bx = (bx0 & 7) * 40 + (bx0 >> 3);   // XCD swizzle (320 = 8*40)
  const int b = bx / 10, p = bx % 10;
  const int ti = (p < 4) ? 0 : (p < 7) ? 1 : (p < 9) ? 2 : 3;
  const int tj = p - ((ti == 0) ? 0 : (ti == 1) ? 3 : (ti == 2) ? 5 : 6);
  const bool diagT = (ti == tj);
  const int i0 = ti * 128, j0 = tj * 128;
  const int bB = b * NS;
  const int rbA = bB + i0, rbB = bB + j0;

  const int tid = threadIdx.x;
  const int lane = tid & 63, wid = tid >> 6;
  const int l31 = lane & 31, hl = lane >> 5;
  const int wr = wid >> 1, wc = wid & 1;

  const size_t offA = (size_t)(rbA + wr * 64 + l31) * ND + hl * 8;
  const size_t offB = (size_t)(rbB + wc * 64 + l31) * ND + hl * 8;
  const unsigned short* pAh = cnhi + offA;
  const unsigned short* pAl = cnlo + offA;
  const unsigned short* pBh = cnhi + offB;
  const unsigned short* pBl = cnlo + offB;

  f32x16 acc[2][2] = {};
  short8 st[3][8];
  GLOADS(st[0], 0);
  GLOADS(st[1], 16);
  #pragma unroll
  for (int it = 0; it < 16; ++it) {
    const int cur = it % 3;
    const int nxt = (it + 2) % 3;
    if (it < 14) GLOADS(st[nxt], (it + 2) * 16);
    GMFMA(st[cur]);
  }

  // ---- epilogue ----
  const float nc0 = nrm[rbB + wc * 64 + l31];
  const float nc1 = nrm[rbB + wc * 64 + 32 + l31];
  float a2 = 0.f, a3 = 0.f, colsum0 = 0.f, colsum1 = 0.f;

  #pragma unroll
  for (int sr = 0; sr < 2; ++sr) {
    #pragma unroll
    for (int r = 0; r < 16; ++r) {
      const int rofs = (r & 3) + 8 * (r >> 2) + 4 * hl;
      const int grow = wr * 64 + sr * 32 + rofs;          // local row 0..127
      const float nr = nrm[rbA + grow];
      float rs = 0.f;
      #pragma unroll
      for (int sc = 0; sc < 2; ++sc) {
        float v = acc[sr][sc][r];
        float adj = (v > 0.3f) ? v : 0.f;
        float q2 = adj * adj;
        a3 += q2;
        a2 += q2 * nr * ((sc == 0) ? nc0 : nc1);
        rs += adj;
        if (sc == 0) colsum0 += adj; else colsum1 += adj;
        int gcol = wc * 64 + sc * 32 + l31;               // local col 0..127
        if (diagT) {
          if (grow == gcol) {
            diag[bB + i0 + grow] = adj;
          } else if (adj > 0.f) {
            unsigned idx = atomicAdd(cnt, 1u);
            if (idx < LIST_CAP) {
              keys[idx] = (unsigned)((bB + i0 + grow) * NS + (j0 + gcol));
              vals[idx] = adj;
            }
          }
        } else if (adj > 0.f) {
          unsigned idx = atomicAdd(cnt, 2u);
          if (idx < LIST_CAP) {
            keys[idx] = (unsigned)((bB + i0 + grow) * NS + (j0 + gcol));
            vals[idx] = adj;
          }
          if (idx + 1u < LIST_CAP) {
            keys[idx + 1u] = (unsigned)((bB + j0 + gcol) * NS + (i0 + grow));
            vals[idx + 1u] = adj;
          }
        }
      }
      rs += __shfl_xor(rs, 1); rs += __shfl_xor(rs, 2); rs += __shfl_xor(rs, 4);
      rs += __shfl_xor(rs, 8); rs += __shfl_xor(rs, 16);
      if (l31 == 0) s_row[wc][grow] = rs;
    }
  }
  colsum0 += __shfl_xor(colsum0, 32);
  colsum1 += __shfl_xor(colsum1, 32);
  if (!diagT && hl == 0) {
    s_col[wr][wc * 64 + l31] = colsum0;
    s_col[wr][wc * 64 + 32 + l31] = colsum1;
  }
  a2 = wave_sum(a2);
  a3 = wave_sum(a3);
  if (lane == 0) { sred[wid] = a2; sred[4 + wid] = a3; }
  __syncthreads();
  if (tid < 128) {
    rowp[tj * 16384 + rbA + tid] = s_row[0][tid] + s_row[1][tid];
    if (!diagT)
      rowp[ti * 16384 + rbB + tid] = s_col[0][tid] + s_col[1][tid];
  }
  if (tid == 0) {
    float f = diagT ? 1.f : 2.f;
    pA2[bx] = f * (sred[0] + sred[1] + sred[2] + sred[3]);
    pA3[bx] = f * (sred[4] + sred[5] + sred[6] + sred[7]);
  }
}

// K3: fused row combine + M build + sparse fixup + A1 partials.
// 4 rows per block (one per wave); each wave's 64 lanes cover the row's 64 f4.
__global__ __launch_bounds__(256)
void k_mrow(const float* __restrict__ ctx, const float* __restrict__ rowp,
            const float* __restrict__ nsq, const float* __restrict__ diag,
            const unsigned* __restrict__ cnt, const unsigned* __restrict__ keys,
            const float* __restrict__ vals,
            unsigned short* __restrict__ Mhi, unsigned short* __restrict__ Mlo,
            float* __restrict__ pA1)
{
  __shared__ float sa[4];
  int tid = threadIdx.x, w = tid >> 6, lane = tid & 63;
  int g = blockIdx.x * 4 + w;
  float r = rowp[g] + rowp[16384 + g] + rowp[32768 + g] + rowp[49152 + g];
  float rr = 1.f / (r + 1e-12f);
  float4 v = ((const float4*)ctx)[(size_t)g * 64 + lane];
  float s = diag[g] * rr;
  float mx = v.x * s, my = v.y * s, mz = v.z * s, mw = v.w * s;
  unsigned c = *cnt; if (c > LIST_CAP) c = LIST_CAP;
  for (unsigned e = 0; e < c; ++e) {
    unsigned key = keys[e];
    if ((key >> 9) == (unsigned)g) {
      float vv = vals[e] * rr;
      unsigned bm = ((unsigned)g & ~511u) | (key & 511u);
      float4 cv = ((const float4*)ctx)[(size_t)bm * 64 + lane];
      mx = fmaf(vv, cv.x, mx); my = fmaf(vv, cv.y, my);
      mz = fmaf(vv, cv.z, mz); mw = fmaf(vv, cv.w, mw);
    }
  }
  ushort4 hi, lo;
  bsplit(mx, hi.x, lo.x); bsplit(my, hi.y, lo.y);
  bsplit(mz, hi.z, lo.z); bsplit(mw, hi.w, lo.w);
  ((ushort4*)Mhi)[(size_t)g * 64 + lane] = hi;
  ((ushort4*)Mlo)[(size_t)g * 64 + lane] = lo;
  if (lane == 0) sa[w] = r * nsq[g];
  __syncthreads();
  if (tid == 0) pA1[blockIdx.x] = sa[0] + sa[1] + sa[2] + sa[3];
}

// K4: C[16384,256] = act(A @ W + bias), register-pipelined like k_gram2.
// MODE 0: relu, write fp32 + bf16 split. MODE 1: write fp32 only.
template<int MODE>
__global__ __launch_bounds__(256, 2)
void k_mm(const unsigned short* __restrict__ Ahi, const unsigned short* __restrict__ Alo,
          const unsigned short* __restrict__ Bthi, const unsigned short* __restrict__ Btlo,
          const float* __restrict__ bias, float* __restrict__ outf,
          unsigned short* __restrict__ Ohi, unsigned short* __restrict__ Olo)
{
  const int i0 = blockIdx.x * 128;
  const int c0 = blockIdx.y * 128;
  const int tid = threadIdx.x;
  const int lane = tid & 63, wid = tid >> 6;
  const int l31 = lane & 31, hl = lane >> 5;
  const int wr = wid >> 1, wc = wid & 1;

  const size_t offA = (size_t)(i0 + wr * 64 + l31) * ND + hl * 8;
  const size_t offB = (size_t)(c0 + wc * 64 + l31) * ND + hl * 8;
  const unsigned short* pAh = Ahi + offA;
  const unsigned short* pAl = Alo + offA;
  const unsigned short* pBh = Bthi + offB;
  const unsigned short* pBl = Btlo + offB;

  f32x16 acc[2][2] = {};
  short8 st[3][8];
  GLOADS(st[0], 0);
  GLOADS(st[1], 16);
  #pragma unroll
  for (int it = 0; it < 16; ++it) {
    const int cur = it % 3;
    const int nxt = (it + 2) % 3;
    if (it < 14) GLOADS(st[nxt], (it + 2) * 16);
    GMFMA(st[cur]);
  }

  const float b0 = bias[c0 + wc * 64 + l31];
  const float b1 = bias[c0 + wc * 64 + 32 + l31];
  #pragma unroll
  for (int sr = 0; sr < 2; ++sr) {
    #pragma unroll
    for (int r = 0; r < 16; ++r) {
      const int rofs = (r & 3) + 8 * (r >> 2) + 4 * hl;
      const size_t grow = (size_t)(i0 + wr * 64 + sr * 32 + rofs);
      #pragma unroll
      for (int sc = 0; sc < 2; ++sc) {
        int gcol = c0 + wc * 64 + sc * 32 + l31;
        float v = acc[sr][sc][r] + ((sc == 0) ? b0 : b1);
        if (MODE == 0) v = fmaxf(v, 0.f);
        outf[grow * ND + gcol] = v;
        if (MODE == 0) {
          unsigned short h, l;
          bsplit(v, h, l);
          Ohi[grow * ND + gcol] = h;
          Olo[grow * ND + gcol] = l;
        }
      }
    }
  }
}

// K5: per-row LayerNorm -> exact GELU -> dot with W_att2 -> wl
__global__ __launch_bounds__(256)
void k_ln(const float* __restrict__ a, const float* __restrict__ g,
          const float* __restrict__ bt, const float* __restrict__ W2,
          const float* __restrict__ b2, float* __restrict__ wl)
{
  int w = threadIdx.x >> 6, lane = threadIdx.x & 63;
  int row = blockIdx.x * 4 + w;
  float4 x = ((const float4*)a)[(size_t)row * 64 + lane];
  float s = x.x + x.y + x.z + x.w;
  float ss = fmaf(x.x, x.x, fmaf(x.y, x.y, fmaf(x.z, x.z, x.w * x.w)));
  s = wave_sum(s); ss = wave_sum(ss);
  float mu = s * (1.f / 256.f);
  float var = ss * (1.f / 256.f) - mu * mu;
  float rstd = rsqrtf(fmaxf(var, 0.f) + 1e-5f);
  float4 gg = ((const float4*)g)[lane];
  float4 bb = ((const float4*)bt)[lane];
  float4 wv = ((const float4*)W2)[lane];
  const float inv_sqrt2 = 0.70710678118654752f;
  float d = 0.f;
  float y = (x.x - mu) * rstd * gg.x + bb.x;
  d = fmaf(0.5f * y * (1.f + erff(y * inv_sqrt2)), wv.x, d);
  y = (x.y - mu) * rstd * gg.y + bb.y;
  d = fmaf(0.5f * y * (1.f + erff(y * inv_sqrt2)), wv.y, d);
  y = (x.z - mu) * rstd * gg.z + bb.z;
  d = fmaf(0.5f * y * (1.f + erff(y * inv_sqrt2)), wv.z, d);
  y = (x.w - mu) * rstd * gg.w + bb.w;
  d = fmaf(0.5f * y * (1.f + erff(y * inv_sqrt2)), wv.w, d);
  d = wave_sum(d);
  if (lane == 0) wl[row] = d + b2[0];
}

// K6: per-(batch, 64-row chunk) masked softmax (recomputed per block) +
// partial weighted pool. 256 blocks.
__global__ __launch_bounds__(256)
void k_pool2(const float* __restrict__ wl, const int* __restrict__ amask,
             const float* __restrict__ h, float* __restrict__ part)
{
  __shared__ float sw[512];
  __shared__ float red[256];
  int b = blockIdx.x >> 3, p = blockIdx.x & 7, t = threadIdx.x;
  float l0 = (amask[b * NS + t]       == 0) ? -INFINITY : wl[b * NS + t];
  float l1 = (amask[b * NS + 256 + t] == 0) ? -INFINITY : wl[b * NS + 256 + t];
  red[t] = fmaxf(l0, l1);
  __syncthreads();
  for (int s = 128; s; s >>= 1) { if (t < s) red[t] = fmaxf(red[t], red[t + s]); __syncthreads(); }
  float mx = red[0];
  __syncthreads();
  float e0 = expf(l0 - mx), e1 = expf(l1 - mx);
  red[t] = e0 + e1;
  __syncthreads();
  for (int s = 128; s; s >>= 1) { if (t < s) red[t] += red[t + s]; __syncthreads(); }
  float inv = 1.f / red[0];
  sw[t] = e0 * inv; sw[256 + t] = e1 * inv;
  __syncthreads();
  const float* hb = h + (size_t)b * NS * ND + (size_t)p * 64 * ND;
  float acc = 0.f;
  #pragma unroll 8
  for (int n = 0; n < 64; ++n) acc = fmaf(sw[p * 64 + n], hb[(size_t)n * ND + t], acc);
  part[(size_t)blockIdx.x * ND + t] = acc;
}

// K7: blocks 0..31: combine pooled partials + logits. Block 32: graph loss.
__global__ __launch_bounds__(256)
void k_final(const float* __restrict__ part, const float* __restrict__ W_out,
             const float* __restrict__ b_out, const float* __restrict__ pA1,
             const float* __restrict__ pA2, const float* __restrict__ pA3,
             float* __restrict__ out)
{
  __shared__ float red[512];
  int t = threadIdx.x;
  if (blockIdx.x < 32) {
    int b = blockIdx.x;
    float pl = 0.f;
    #pragma unroll
    for (int p = 0; p < 8; ++p) pl += part[(size_t)(b * 8 + p) * ND + t];
    red[t]       = pl * W_out[t * 2 + 0];
    red[256 + t] = pl * W_out[t * 2 + 1];
    __syncthreads();
    for (int s = 128; s; s >>= 1) {
      if (t < s) { red[t] += red[t + s]; red[256 + t] += red[256 + t + s]; }
      __syncthreads();
    }
    if (t == 0) {
      out[b * 2 + 0] = red[0]   + b_out[0];
      out[b * 2 + 1] = red[256] + b_out[1];
    }
  } else {
    float r1 = 0.f;
    #pragma unroll
    for (int i = 0; i < 16; ++i) r1 += pA1[i * 256 + t];
    float r2 = pA2[t] + ((t < 64) ? pA2[256 + t] : 0.f);
    float r3 = pA3[t] + ((t < 64) ? pA3[256 + t] : 0.f);
    red[t] = r1; red[256 + t] = r2;
    __syncthreads();
    for (int s = 128; s; s >>= 1) {
      if (t < s) { red[t] += red[t + s]; red[256 + t] += red[256 + t + s]; }
      __syncthreads();
    }
    r1 = red[0]; r2 = red[256];
    __syncthreads();
    red[t] = r3;
    __syncthreads();
    for (int s = 128; s; s >>= 1) { if (t < s) red[t] += red[t + s]; __syncthreads(); }
    if (t == 0) {
      float smooth = 0.2f * (r1 - r2) * (1.f / (32.f * 512.f * 512.f));
      float spars  = 0.1f * red[0] * (1.f / (512.f * 512.f)) * (1.f / 32.f);
      out[64] = smooth + spars;
    }
  }
}

extern "C" void kernel_launch(void* const* d_in, const int* in_sizes, int n_in,
                              void* d_out, int out_size, void* d_ws, size_t ws_size,
                              hipStream_t stream)
{
  (void)in_sizes; (void)n_in; (void)out_size; (void)ws_size;
  const float* ctx    = (const float*)d_in[0];
  const int*   amask  = (const int*)d_in[1];
  const float* W_gcn  = (const float*)d_in[2];
  const float* b_gcn  = (const float*)d_in[3];
  const float* W_att1 = (const float*)d_in[4];
  const float* b_att1 = (const float*)d_in[5];
  const float* ln_g   = (const float*)d_in[6];
  const float* ln_b   = (const float*)d_in[7];
  const float* W_att2 = (const float*)d_in[8];
  const float* b_att2 = (const float*)d_in[9];
  const float* W_out  = (const float*)d_in[10];
  const float* b_out  = (const float*)d_in[11];
  float* out = (float*)d_out;

  float* ws = (float*)d_ws;
  // W0 (16.8 MB): cn hi/lo, later reused as h hi/lo
  unsigned short* cnhi = (unsigned short*)ws;
  unsigned short* cnlo = (unsigned short*)(ws + 2097152);
  unsigned short* hhi  = cnhi;
  unsigned short* hlo  = cnlo;
  // W1 (16.8 MB): h fp32
  float* hbuf = ws + 4194304;
  // W2 (16.8 MB): M hi/lo, later reused as 'a' fp32
  unsigned short* Mhi = (unsigned short*)(ws + 8388608);
  unsigned short* Mlo = (unsigned short*)(ws + 8388608 + 2097152);
  float* abuf = ws + 8388608;
  // small region
  float* sp   = ws + 12582912;
  float* nrm  = sp;            sp += 16384;
  float* nsq  = sp;            sp += 16384;
  float* rowp = sp;            sp += 65536;
  float* diag = sp;            sp += 16384;
  float* wl   = sp;            sp += 16384;
  float* pA1  = sp;            sp += 4096;
  float* pA2  = sp;            sp += 512;
  float* pA3  = sp;            sp += 512;
  float* part = sp;            sp += 65536;
  unsigned* cnt  = (unsigned*)sp;  sp += 64;
  unsigned* keys = (unsigned*)sp;  sp += 32768;
  float* vals = sp;            sp += 32768;
  unsigned short* wgthi = (unsigned short*)sp; sp += 32768;
  unsigned short* wgtlo = (unsigned short*)sp; sp += 32768;
  unsigned short* wathi = (unsigned short*)sp; sp += 32768;
  unsigned short* watlo = (unsigned short*)sp; sp += 32768;

  k_prep<<<4608, 256, 0, stream>>>(ctx, W_gcn, W_att1, nrm, nsq, cnhi, cnlo,
                                   wgthi, wgtlo, wathi, watlo, cnt);
  k_gram2<<<320, 256, 0, stream>>>(cnhi, cnlo, nrm, rowp, diag, pA2, pA3,
                                   cnt, keys, vals);
  k_mrow<<<4096, 256, 0, stream>>>(ctx, rowp, nsq, diag, cnt, keys, vals,
                                   Mhi, Mlo, pA1);
  k_mm<0><<<dim3(128, 2), 256, 0, stream>>>(Mhi, Mlo, wgthi, wgtlo, b_gcn, hbuf, hhi, hlo);
  k_mm<1><<<dim3(128, 2), 256, 0, stream>>>(hhi, hlo, wathi, watlo, b_att1, abuf, nullptr, nullptr);
  k_ln<<<4096, 256, 0, stream>>>(abuf, ln_g, ln_b, W_att2, b_att2, wl);
  k_pool2<<<256, 256, 0, stream>>>(wl, amask, hbuf, part);
  k_final<<<33, 256, 0, stream>>>(part, W_out, b_out, pA1, pA2, pA3, out);
}